// Round 1
// baseline (2644.444 us; speedup 1.0000x reference)
//
#include <hip/hip_runtime.h>
#include <hip/hip_bf16.h>
#include <math.h>

#define B_    16
#define CI_   512
#define CO_   512
#define HH    64
#define WW    64
#define STYLE_ 512

typedef __bf16 bf16x8 __attribute__((ext_vector_type(8)));
typedef float f32x4 __attribute__((ext_vector_type(4)));

// ---------- kernel 1: s[b][ci] = style[b] . mod_w[ci] / sqrt(512) + mod_b[ci]
__global__ void k_style(const float* __restrict__ style, const float* __restrict__ mod_w,
                        const float* __restrict__ mod_b, float* __restrict__ s_out) {
    int b  = blockIdx.x;
    int ci = threadIdx.x;
    const float scale = 0.044194173824159216f; // 1/sqrt(512)
    float acc = 0.f;
    const float* st = style + b * STYLE_;
    const float* mw = mod_w + (size_t)ci * STYLE_;
    for (int j = 0; j < STYLE_; ++j) acc += st[j] * mw[j];
    s_out[b * CI_ + ci] = acc * scale + mod_b[ci];
}

// ---------- kernel 2: wsq[co][ci] = sum_tap weight^2
__global__ void k_wsq(const float* __restrict__ weight, float* __restrict__ wsq) {
    int p = blockIdx.x * blockDim.x + threadIdx.x; // co*512 + ci
    const float* wp = weight + (size_t)p * 9;
    float acc = 0.f;
    for (int t = 0; t < 9; ++t) { float v = wp[t]; acc += v * v; }
    wsq[p] = acc;
}

// ---------- kernel 3: demod[b][co] = rsqrt(w_scale^2 * sum_ci s^2 * wsq + 1e-8)
__global__ void k_demod(const float* __restrict__ s, const float* __restrict__ wsq,
                        float* __restrict__ demod) {
    int b = blockIdx.x, co = threadIdx.x;
    const float w_scale2 = 1.0f / 4608.0f;
    float acc = 0.f;
    const float* sb = s + b * CI_;
    const float* wq = wsq + (size_t)co * CI_;
    for (int ci = 0; ci < CI_; ++ci) { float sv = sb[ci]; acc += sv * sv * wq[ci]; }
    demod[b * CO_ + co] = 1.0f / sqrtf(acc * w_scale2 + 1e-8f);
}

// ---------- kernel 4: modulated conv as 9-tap shifted implicit GEMM (bf16 MFMA)
#define BM 64
#define CK 32
#define XPAD 40   // row stride in bf16 elems: 80B = 20 dwords -> conflict-free b128, 16B aligned

__global__ __launch_bounds__(256) void k_conv(
    const float* __restrict__ x, const float* __restrict__ weight,
    const float* __restrict__ s, const float* __restrict__ demod,
    float* __restrict__ out)
{
    __shared__ __align__(16) __bf16 Xs[3][66][XPAD];   // [row r][x+1 (halo)][ci]
    __shared__ __align__(16) __bf16 Ws[9][BM][XPAD];   // [tap][co][ci]

    const int tid  = threadIdx.x;
    const int lane = tid & 63;
    const int wave = tid >> 6;
    const int co0  = blockIdx.x * BM;
    const int y    = blockIdx.y;
    const int b    = blockIdx.z;
    const float w_scale = 0.014731391274719739f; // 1/sqrt(512*9)

    // zero halo columns (x = -1 and x = 64) once; staging never overwrites them
    if (tid < 192) {
        int ci = tid & 31, c = (tid >> 5) & 1, r = tid >> 6;
        Xs[r][c * 65][ci] = (__bf16)0.0f;
    }

    f32x4 acc[4];
    for (int i = 0; i < 4; ++i) acc[i] = (f32x4){0.f, 0.f, 0.f, 0.f};

    const int m  = lane & 15;         // A row (co) / B col (x) within 16-tile
    const int k0 = (lane >> 4) << 3;  // k-group: 8 consecutive ci

    for (int ci0 = 0; ci0 < CI_; ci0 += CK) {
        // ---- stage X chunk: 3 rows x 32 ci x 64 px, fp32 -> bf16, x-major/ci-minor
        for (int i = tid; i < 3 * CK * WW; i += 256) {
            int xx = i & 63;
            int ci = (i >> 6) & (CK - 1);
            int r  = i >> 11;
            int yy = y + r - 1;
            float v = 0.f;
            if (yy >= 0 && yy < HH)
                v = x[((size_t)(b * CI_ + ci0 + ci) * HH + yy) * WW + xx];
            Xs[r][xx + 1][ci] = (__bf16)v;
        }
        // ---- stage W chunk: 64 co x 32 ci x 9 taps, modulate+demodulate while converting
        {
            int ci = tid & 31;                       // fixed per thread across p-iters
            float sv = s[b * CI_ + ci0 + ci] * w_scale;
            for (int p = tid; p < BM * CK; p += 256) {
                int co = p >> 5;
                float alpha = sv * demod[b * CO_ + co0 + co];
                const float* wp = weight + ((size_t)(co0 + co) * CI_ + ci0 + ci) * 9;
                for (int t = 0; t < 9; ++t)
                    Ws[t][co][ci] = (__bf16)(wp[t] * alpha);
            }
        }
        __syncthreads();

        // ---- compute: wave owns 16 co rows x 64 x cols
        bf16x8 a[9];
        for (int t = 0; t < 9; ++t)
            a[t] = *(const bf16x8*)&Ws[t][wave * 16 + m][k0];
        for (int nt = 0; nt < 4; ++nt) {
            for (int kh = 0; kh < 3; ++kh)
                for (int kw = 0; kw < 3; ++kw) {
                    bf16x8 bf = *(const bf16x8*)&Xs[kh][nt * 16 + m + kw][k0];
                    acc[nt] = __builtin_amdgcn_mfma_f32_16x16x32_bf16(a[kh * 3 + kw], bf, acc[nt], 0, 0, 0);
                }
        }
        __syncthreads();
    }

    // ---- epilogue: D row = (lane>>4)*4 + r, col = lane&15
    int mrow = co0 + wave * 16 + ((lane >> 4) << 2);
    for (int nt = 0; nt < 4; ++nt) {
        int xcol = nt * 16 + m;
        float* op = out + ((size_t)(b * CO_ + mrow) * HH + y) * WW + xcol;
        op[0]      = acc[nt][0];
        op[4096]   = acc[nt][1];
        op[8192]   = acc[nt][2];
        op[12288]  = acc[nt][3];
    }
}

extern "C" void kernel_launch(void* const* d_in, const int* in_sizes, int n_in,
                              void* d_out, int out_size, void* d_ws, size_t ws_size,
                              hipStream_t stream) {
    const float* x      = (const float*)d_in[0];
    const float* style  = (const float*)d_in[1];
    const float* weight = (const float*)d_in[2];
    const float* mod_w  = (const float*)d_in[3];
    const float* mod_b  = (const float*)d_in[4];
    float* out = (float*)d_out;

    float* ws    = (float*)d_ws;
    float* s_buf = ws;                 // 16*512
    float* demod = ws + 8192;          // 16*512
    float* wsq   = ws + 16384;         // 512*512

    k_style<<<dim3(B_), dim3(CI_), 0, stream>>>(style, mod_w, mod_b, s_buf);
    k_wsq<<<dim3(CO_), dim3(CI_), 0, stream>>>(weight, wsq);
    k_demod<<<dim3(B_), dim3(CO_), 0, stream>>>(s_buf, wsq, demod);
    k_conv<<<dim3(CO_ / BM, HH, B_), dim3(256), 0, stream>>>(x, weight, s_buf, demod, out);
}

// Round 2
// 400.490 us; speedup vs baseline: 6.6030x; 6.6030x over previous
//
#include <hip/hip_runtime.h>
#include <hip/hip_bf16.h>
#include <math.h>

#define B_     16
#define CI_    512
#define CO_    512
#define HH     64
#define WW     64
#define STYLE_ 512

typedef __bf16 bf16x8 __attribute__((ext_vector_type(8)));
typedef float f32x4 __attribute__((ext_vector_type(4)));

// ---- workspace layout (bytes) ----
#define WS_S     0                    // s[b][ci] f32, 32 KB
#define WS_DEMOD 32768                // demod[b][co] f32, 32 KB
#define WS_WSQ   65536                // wsq[ci][co] f32 (transposed), 1 MB
#define WS_WB    1114112              // wb[t][co][ci] bf16, 9*512*512*2 = 4.7 MB
#define WS_XS    5832704              // xs[b][y][x][ci] bf16, 67 MB

// ---------- s[b][ci] = style[b] . mod_w[ci] / sqrt(512) + mod_b[ci]
__global__ void k_style(const float* __restrict__ style, const float* __restrict__ mod_w,
                        const float* __restrict__ mod_b, float* __restrict__ s_out) {
    int b  = blockIdx.x;
    int ci = threadIdx.x;
    const float scale = 0.044194173824159216f; // 1/sqrt(512)
    float acc = 0.f;
    const float* st = style + b * STYLE_;
    const float* mw = mod_w + (size_t)ci * STYLE_;
    for (int j = 0; j < STYLE_; ++j) acc += st[j] * mw[j];
    s_out[b * CI_ + ci] = acc * scale + mod_b[ci];
}

// ---------- wsq[ci][co] = sum_tap weight[co][ci][t]^2  (transposed for coalesced demod reads)
__global__ void k_wsq(const float* __restrict__ weight, float* __restrict__ wsq) {
    int p = blockIdx.x * blockDim.x + threadIdx.x; // co*512 + ci
    int co = p >> 9, ci = p & 511;
    const float* wp = weight + (size_t)p * 9;
    float acc = 0.f;
    for (int t = 0; t < 9; ++t) { float v = wp[t]; acc += v * v; }
    wsq[(size_t)ci * CO_ + co] = acc;
}

// ---------- demod[b][co] = rsqrt(w_scale^2 * sum_ci s^2 * wsq + 1e-8)
__global__ void k_demod(const float* __restrict__ s, const float* __restrict__ wsq,
                        float* __restrict__ demod) {
    int b = blockIdx.x, co = threadIdx.x;
    const float w_scale2 = 1.0f / 4608.0f;
    float acc = 0.f;
    const float* sb = s + b * CI_;
    for (int ci = 0; ci < CI_; ++ci) { float sv = sb[ci]; acc += sv * sv * wsq[(size_t)ci * CO_ + co]; }
    demod[b * CO_ + co] = 1.0f / sqrtf(acc * w_scale2 + 1e-8f);
}

// ---------- wb[t][co][ci] = bf16(weight[co][ci][t])
__global__ __launch_bounds__(256) void k_wb(const float* __restrict__ weight, __bf16* __restrict__ wb) {
    int p = blockIdx.x * 256 + threadIdx.x;   // co*512 + ci
    int co = p >> 9, ci = p & 511;
    const float* wp = weight + (size_t)p * 9;
    #pragma unroll
    for (int t = 0; t < 9; ++t)
        wb[((size_t)t * CO_ + co) * CI_ + ci] = (__bf16)wp[t];
}

// ---------- xs[b][y][x][ci] = bf16(x[b][ci][y][x] * s[b][ci] * w_scale)  (NHWC transpose)
__global__ __launch_bounds__(256) void k_xs(const float* __restrict__ x, const float* __restrict__ s,
                                            __bf16* __restrict__ xs) {
    __shared__ float Lt[64][65];
    const int y = blockIdx.x, b = blockIdx.y;
    const int tid = threadIdx.x;
    const float w_scale = 0.014731391274719739f; // 1/sqrt(512*9)
    for (int ci0 = 0; ci0 < CI_; ci0 += 64) {
        for (int i = tid; i < 64 * 64; i += 256) {
            int ci = i >> 6, xx = i & 63;
            Lt[ci][xx] = x[((size_t)(b * CI_ + ci0 + ci) * HH + y) * WW + xx]
                         * s[b * CI_ + ci0 + ci] * w_scale;
        }
        __syncthreads();
        for (int o = tid; o < 512; o += 256) {
            int xx = o >> 3, oct = o & 7;
            bf16x8 v;
            #pragma unroll
            for (int j = 0; j < 8; ++j) v[j] = (__bf16)Lt[oct * 8 + j][xx];
            *(bf16x8*)&xs[(((size_t)(b * HH + y) * WW + xx) << 9) + ci0 + oct * 8] = v;
        }
        __syncthreads();
    }
}

// ---------- conv: pure bf16 implicit GEMM, 9 shifted taps, demod epilogue
// block: 64 co x 4 y x 64 x, 4 waves (wave = one y-row, 64co x 64x, m_t=4 n_t=4)
#define XPAD 40   // row stride 80 B = 20 dwords -> conflict-balanced b128
__global__ __launch_bounds__(256) void k_conv(
    const __bf16* __restrict__ xs, const __bf16* __restrict__ wb,
    const float* __restrict__ demod, float* __restrict__ out)
{
    __shared__ __align__(16) __bf16 Xs[6][66][XPAD];   // rows y0-1..y0+4, x+1 halo, ci
    __shared__ __align__(16) __bf16 Ws[9][64][XPAD];   // tap, co, ci

    const int tid  = threadIdx.x;
    const int lane = tid & 63;
    const int wy   = tid >> 6;            // wave owns output row y0+wy
    const int co0  = blockIdx.x * 64;
    const int y0   = blockIdx.y * 4;
    const int b    = blockIdx.z;

    // zero x-halo columns (persist across chunks: staging only writes x=1..64)
    for (int i = tid; i < 6 * 2 * 32; i += 256) {
        int ci = i & 31, c = (i >> 5) & 1, r = i >> 6;
        Xs[r][c * 65][ci] = (__bf16)0.0f;
    }

    f32x4 acc[4][4];
    #pragma unroll
    for (int mi = 0; mi < 4; ++mi)
        #pragma unroll
        for (int nt = 0; nt < 4; ++nt) acc[mi][nt] = (f32x4){0.f, 0.f, 0.f, 0.f};

    const int m  = lane & 15;
    const int g  = lane >> 4;
    const int k0 = g << 3;

    for (int ci0 = 0; ci0 < CI_; ci0 += 32) {
        // ---- stage X: 6 rows x 64 x x 32 ci (bf16x8 copy), zeros outside y range
        #pragma unroll
        for (int it = 0; it < 6; ++it) {
            int i  = tid + it * 256;
            int cq = i & 3, xx = (i >> 2) & 63, r = i >> 8;
            int yy = y0 + r - 1;
            bf16x8 v;
            #pragma unroll
            for (int j = 0; j < 8; ++j) v[j] = (__bf16)0.0f;
            if (yy >= 0 && yy < HH)
                v = *(const bf16x8*)&xs[(((size_t)(b * HH + yy) * WW + xx) << 9) + ci0 + cq * 8];
            *(bf16x8*)&Xs[r][xx + 1][cq * 8] = v;
        }
        // ---- stage W: 9 taps x 64 co x 32 ci (bf16x8 copy)
        #pragma unroll
        for (int it = 0; it < 9; ++it) {
            int i  = tid + it * 256;
            int cq = i & 3, co = (i >> 2) & 63, t = i >> 8;
            bf16x8 v = *(const bf16x8*)&wb[(((size_t)t * CO_ + co0 + co) << 9) + ci0 + cq * 8];
            *(bf16x8*)&Ws[t][co][cq * 8] = v;
        }
        __syncthreads();

        // ---- compute: 9 taps x (4 a-frags, 4 nt x 4 MFMA) = 144 MFMA / 72 b128 reads
        #pragma unroll
        for (int kh = 0; kh < 3; ++kh) {
            #pragma unroll
            for (int kw = 0; kw < 3; ++kw) {
                const int t = kh * 3 + kw;
                bf16x8 a0 = *(const bf16x8*)&Ws[t][ 0 + m][k0];
                bf16x8 a1 = *(const bf16x8*)&Ws[t][16 + m][k0];
                bf16x8 a2 = *(const bf16x8*)&Ws[t][32 + m][k0];
                bf16x8 a3 = *(const bf16x8*)&Ws[t][48 + m][k0];
                #pragma unroll
                for (int nt = 0; nt < 4; ++nt) {
                    bf16x8 bv = *(const bf16x8*)&Xs[wy + kh][nt * 16 + m + kw][k0];
                    acc[0][nt] = __builtin_amdgcn_mfma_f32_16x16x32_bf16(a0, bv, acc[0][nt], 0, 0, 0);
                    acc[1][nt] = __builtin_amdgcn_mfma_f32_16x16x32_bf16(a1, bv, acc[1][nt], 0, 0, 0);
                    acc[2][nt] = __builtin_amdgcn_mfma_f32_16x16x32_bf16(a2, bv, acc[2][nt], 0, 0, 0);
                    acc[3][nt] = __builtin_amdgcn_mfma_f32_16x16x32_bf16(a3, bv, acc[3][nt], 0, 0, 0);
                }
            }
        }
        __syncthreads();
    }

    // ---- epilogue: out[b][co][y][x] = acc * demod[b][co]
    const int y = y0 + wy;
    #pragma unroll
    for (int mi = 0; mi < 4; ++mi) {
        #pragma unroll
        for (int j = 0; j < 4; ++j) {
            const int co = co0 + mi * 16 + g * 4 + j;
            const float dm = demod[b * CO_ + co];
            float* op = out + ((size_t)(b * CO_ + co) * HH + y) * WW;
            #pragma unroll
            for (int nt = 0; nt < 4; ++nt)
                op[nt * 16 + m] = acc[mi][nt][j] * dm;
        }
    }
}

extern "C" void kernel_launch(void* const* d_in, const int* in_sizes, int n_in,
                              void* d_out, int out_size, void* d_ws, size_t ws_size,
                              hipStream_t stream) {
    const float* x      = (const float*)d_in[0];
    const float* style  = (const float*)d_in[1];
    const float* weight = (const float*)d_in[2];
    const float* mod_w  = (const float*)d_in[3];
    const float* mod_b  = (const float*)d_in[4];
    float* out = (float*)d_out;

    char* wsb = (char*)d_ws;
    float*  s_buf = (float*)(wsb + WS_S);
    float*  demod = (float*)(wsb + WS_DEMOD);
    float*  wsq   = (float*)(wsb + WS_WSQ);
    __bf16* wb    = (__bf16*)(wsb + WS_WB);
    __bf16* xs    = (__bf16*)(wsb + WS_XS);

    k_style<<<dim3(B_), dim3(CI_), 0, stream>>>(style, mod_w, mod_b, s_buf);
    k_wsq<<<dim3(CO_ * CI_ / 512), dim3(512), 0, stream>>>(weight, wsq);
    k_demod<<<dim3(B_), dim3(CO_), 0, stream>>>(s_buf, wsq, demod);
    k_wb<<<dim3(CO_ * CI_ / 256), dim3(256), 0, stream>>>(weight, wb);
    k_xs<<<dim3(HH, B_), dim3(256), 0, stream>>>(x, s_buf, xs);
    k_conv<<<dim3(CO_ / 64, HH / 4, B_), dim3(256), 0, stream>>>(xs, wb, demod, out);
}